// Round 4
// baseline (241.136 us; speedup 1.0000x reference)
//
#include <hip/hip_runtime.h>
#include <stdint.h>

// WeightsDropout: per row of 4096 f32 (uniform in (1e-4,1)), drop the 2048
// smallest (stable tie-break: smaller index dropped first), softmax survivors.
//
// R7: ONE WAVE PER ROW, ZERO __syncthreads. 64 lanes x 64 elems/lane
// (16 dwordx4/lane). All phases wave-internal:
//   - hist/candidates live in wave-private LDS (only lgkmcnt fences needed,
//     via __threadfence_block; no cross-wave rendezvous)
//   - reductions/broadcasts via __shfl / __ballot (crossing bucket and
//     threshold broadcast with ballot+ffs+shfl, no LDS round trip)
//   - candidate gather via ballot-slotting (no atomics for slots)
// Rationale: R4-R6 all sat at VALU ~33%, HBM ~30% regardless of occupancy
// (48->67%) -> bound by the 6-8 cross-wave barrier phases per row, not by
// wave count. Removing barriers lets waves free-run; VALU floor ~9us,
// HBM floor ~32-42us -> memory-roofline target.
// Max subtraction removed (inputs < 1 -> exp(x) <= e; softmax shift-invariant).
// Output non-temporal. Exact wave-level bisection fallback for correctness
// on any input (never taken for uniform data).
constexpr int N     = 4096;
constexpr int KSEL  = 2048;          // int(N * 0.5)
constexpr int BLOCK = 256;
constexpr int NWAVE = BLOCK / 64;    // 4 rows per block
constexpr int EPL   = 64;            // elements per lane
constexpr int NB    = 256;           // fine buckets over the band
constexpr int CAP   = 64;            // candidate capacity (E[#]=1.6)
constexpr float P1  = 0.45f;
constexpr float P2  = 0.55f;
constexpr float BSCALE = 2560.0f;    // NB / (P2 - P1)

typedef float vfloat4 __attribute__((ext_vector_type(4)));

__global__ __launch_bounds__(BLOCK, 4)
void wdrop_kernel(const float* __restrict__ w, float* __restrict__ out) {
    const int t = threadIdx.x, wid = t >> 6, lane = t & 63;
    const uint64_t row = (uint64_t)blockIdx.x * NWAVE + wid;

    __shared__ alignas(16) int hist[NWAVE][NB];   // wave-private segments
    __shared__ uint32_t cb[NWAVE][CAP];
    __shared__ int      ci[NWAVE][CAP];

    // ---- load row: 16 x dwordx4 per lane, all issued up front
    uint32_t v[EPL];
    {
        const uint4* wf = (const uint4*)(w + row * N);
        uint4 u[16];
#pragma unroll
        for (int j = 0; j < 16; ++j) u[j] = wf[j * 64 + lane];
#pragma unroll
        for (int j = 0; j < 16; ++j) {
            v[j*4+0] = u[j].x; v[j*4+1] = u[j].y;
            v[j*4+2] = u[j].z; v[j*4+3] = u[j].w;
        }
    }

    // ---- zero own hist (4 ints/lane), fence (wave-local ordering only)
    ((int4*)hist[wid])[lane] = int4{0, 0, 0, 0};
    __threadfence_block();

    // ---- pass 1: below-band count + fine histogram of [P1,P2)
    int clo = 0;
#pragma unroll
    for (int e = 0; e < EPL; ++e) {
        const float f = __uint_as_float(v[e]);
        clo += (f < P1);
        if (f >= P1 && f < P2)
            atomicAdd(&hist[wid][min((int)((f - P1) * BSCALE), NB - 1)], 1);
    }
#pragma unroll
    for (int off = 32; off > 0; off >>= 1) clo += __shfl_xor(clo, off, 64);
    __threadfence_block();

    // ---- scan own hist (int4/lane + shuffle scan), find crossing bucket
    const int4 hh = ((const int4*)hist[wid])[lane];
    const int a0 = hh.x, a1 = a0 + hh.y, a2 = a1 + hh.z, a3 = a2 + hh.w;
    int sc = a3;
#pragma unroll
    for (int off = 1; off < 64; off <<= 1) {
        const int u = __shfl_up(sc, off, 64);
        if (lane >= off) sc += u;
    }
    const int base = sc - a3;                 // exclusive prefix of lane's 4
    const int tot  = __shfl(sc, 63, 64);      // total band count (uniform)
    bool fastp = (clo < KSEL) && (clo + tot >= KSEL);   // k-th in [P1,P2)
    int selb = -1, jms = 0;
    if (fastp) {
        const int jrank = KSEL - clo;         // 1-indexed rank within band
        const int inc[4] = {base + a0, base + a1, base + a2, base + a3};
        const int exc[4] = {base, base + a0, base + a1, base + a2};
#pragma unroll
        for (int i = 0; i < 4; ++i)
            if (exc[i] < jrank && jrank <= inc[i]) {
                selb = lane * 4 + i;
                jms  = jrank - exc[i] - 1;    // 0-indexed rank in bucket
            }
        // broadcast crossing bucket from the (single) finding lane
        const unsigned long long b = __ballot(selb >= 0);
        const int src = __ffsll((unsigned long long)b) - 1;
        selb = __shfl(selb, src, 64);
        jms  = __shfl(jms,  src, 64);
    }

    // ---- gather candidates in crossing bucket via ballot-slotting
    uint32_t thrT = 0; int thrI = 0;
    if (fastp) {
        int cn = 0;
#pragma unroll
        for (int e = 0; e < EPL; ++e) {
            const float f = __uint_as_float(v[e]);
            const bool in = (f >= P1) && (f < P2) &&
                            (min((int)((f - P1) * BSCALE), NB - 1) == selb);
            const unsigned long long m = __ballot(in);
            if (in) {
                const int slot = cn + __popcll(m & ((1ull << lane) - 1ull));
                if (slot < CAP) {
                    cb[wid][slot] = v[e];
                    ci[wid][slot] = ((e >> 2) * 64 + lane) * 4 + (e & 3);
                }
            }
            cn += __popcll(m);
        }
        if (cn > CAP) fastp = false;
        if (fastp) {
            __threadfence_block();
            // exact lex rank among candidates -> k-th smallest (bits, idx)
            bool found = false; uint32_t myT = 0; int myI = 0;
            if (lane < cn) {
                const uint32_t myb = cb[wid][lane]; const int myi = ci[wid][lane];
                int rank = 0;
                for (int q = 0; q < cn; ++q)
                    rank += (cb[wid][q] < myb) ||
                            (cb[wid][q] == myb && ci[wid][q] < myi);
                if (rank == jms) { found = true; myT = myb; myI = myi; }
            }
            const unsigned long long b = __ballot(found);
            const int src = __ffsll((unsigned long long)b) - 1;
            thrT = (uint32_t)__shfl((int)myT, src, 64);
            thrI = __shfl(myI, src, 64);
        }
    }

    // ---- exact wave-level bisection fallback (never taken for uniform data)
    if (!fastp) {
        uint32_t blo = 0u, bhi = 0x7f7fffffu;
        while (blo < bhi) {
            const uint32_t mid = blo + ((bhi - blo) >> 1);
            int c = 0;
#pragma unroll
            for (int e = 0; e < EPL; ++e) c += (v[e] <= mid);
#pragma unroll
            for (int off = 32; off > 0; off >>= 1) c += __shfl_xor(c, off, 64);
            if (c >= KSEL) bhi = mid; else blo = mid + 1;
        }
        const uint32_t T = blo;
        int c = 0;
#pragma unroll
        for (int e = 0; e < EPL; ++e) c += (v[e] < T);
#pragma unroll
        for (int off = 32; off > 0; off >>= 1) c += __shfl_xor(c, off, 64);
        const int need = KSEL - c;
        int ilo = 0, ihi = N - 1;
        while (ilo < ihi) {
            const int imid = (ilo + ihi) >> 1;
            int cc = 0;
#pragma unroll
            for (int e = 0; e < EPL; ++e) {
                const int idx = ((e >> 2) * 64 + lane) * 4 + (e & 3);
                cc += (v[e] == T && idx <= imid);
            }
#pragma unroll
            for (int off = 32; off > 0; off >>= 1) cc += __shfl_xor(cc, off, 64);
            if (cc >= need) ihi = imid; else ilo = imid + 1;
        }
        thrT = T; thrI = ilo;
    }

    // ---- keep + exp (no max: inputs < 1) + wave sum, scale + NT store
    float acc = 0.0f;
#pragma unroll
    for (int e = 0; e < EPL; ++e) {
        const int idx = ((e >> 2) * 64 + lane) * 4 + (e & 3);
        const bool keep = (v[e] > thrT) || (v[e] == thrT && idx > thrI);
        const float ev = keep ? __expf(__uint_as_float(v[e])) : 0.0f;
        v[e] = __float_as_uint(ev);
        acc += ev;
    }
#pragma unroll
    for (int off = 32; off > 0; off >>= 1) acc += __shfl_xor(acc, off, 64);
    const float inv = 1.0f / acc;

    vfloat4* of = (vfloat4*)(out + row * N);
#pragma unroll
    for (int j = 0; j < 16; ++j) {
        vfloat4 o;
        o.x = __uint_as_float(v[j*4+0]) * inv;
        o.y = __uint_as_float(v[j*4+1]) * inv;
        o.z = __uint_as_float(v[j*4+2]) * inv;
        o.w = __uint_as_float(v[j*4+3]) * inv;
        __builtin_nontemporal_store(o, &of[j * 64 + lane]);
    }
}

extern "C" void kernel_launch(void* const* d_in, const int* in_sizes, int n_in,
                              void* d_out, int out_size, void* d_ws, size_t ws_size,
                              hipStream_t stream) {
    const float* w = (const float*)d_in[0];
    float* out = (float*)d_out;
    const int rows = in_sizes[0] / N;            // 8192
    wdrop_kernel<<<rows / NWAVE, BLOCK, 0, stream>>>(w, out);
}

// Round 6
// 239.540 us; speedup vs baseline: 1.0067x; 1.0067x over previous
//
#include <hip/hip_runtime.h>
#include <stdint.h>

// WeightsDropout: per row of 4096 f32 (uniform in (1e-4,1)), drop the 2048
// smallest (stable tie-break: smaller index dropped first), softmax survivors.
//
// R8b: identical to R8 (bench infra failed; kernel never ran).
// STREAMING, NO PER-THREAD ROW ARRAY. R4-R7 all held the row in a big
// register array; rocprof showed VGPR_Count (36/24/64) far below the live-value
// count -> compiler spilled to scratch, and scratch round-trips were the
// invariant ~85-90us critical path (VALU ~30%, HBM ~30% regardless of
// structure/occupancy). R8 streams instead:
//   pass1: read row once, count <P1, LDS hist + per-bucket exp-sums
//          (ds_add_f32), wave-partial sum of exp(x>=P2), band elems appended
//          to an LDS pool (ballot-compacted, ~410 entries).
//   wave0: dual shuffle-scan (counts+sums) -> crossing bucket; exact lex rank
//          over pool candidates; survivor exp-sum ANALYTICALLY =
//          sumHigh + suffix(bucket sums) + in-bucket correction. No sum pass.
//   pass2: re-read row (L2-hot, no extra HBM), keep -> exp*inv, NT store.
// 3 barriers/row, ~40 VGPR, 8.7KB LDS -> 8 blocks/CU (100% occupancy), loads
// in both passes deeply pipelined (no reg pressure).
// Max subtraction removed (inputs < 1 -> exp(x) <= e; softmax shift-invariant).
// Exact block-level bisection fallback (global re-reads; correctness only,
// never taken for uniform data). All conditional __syncthreads are gated by
// the block-uniform shared bFlag -> no divergent-barrier deadlock.
constexpr int N     = 4096;
constexpr int KSEL  = 2048;          // int(N * 0.5)
constexpr int BLOCK = 256;
constexpr int NW    = BLOCK / 64;    // 4 waves
constexpr int VPT   = 4;             // uint4 loads per thread (16 elems)
constexpr int NB    = 256;           // fine buckets over the band
constexpr int POOL  = 768;           // band-elem pool (E[#]=410, sd=19)
constexpr int CAND  = 64;            // crossing-bucket candidates (E[#]=1.6)
constexpr float P1  = 0.45f;
constexpr float P2  = 0.55f;
constexpr float BSCALE = 2560.0f;    // NB / (P2 - P1)

typedef float vfloat4 __attribute__((ext_vector_type(4)));

__global__ __launch_bounds__(BLOCK, 8)
void wdrop_kernel(const float* __restrict__ w, float* __restrict__ out) {
    const int t = threadIdx.x, wid = t >> 6, lane = t & 63;
    const uint64_t row = blockIdx.x;
    const float* rp = w + row * N;

    __shared__ alignas(16) int   hist[NB];     // band bucket counts
    __shared__ alignas(16) float hsum[NB];     // band bucket exp-sums
    __shared__ uint2    pool[POOL];            // band elems (bits, idx)
    __shared__ int      pcnt;
    __shared__ int      wclo[NW];              // int reduce slots
    __shared__ float    whigh[NW];             // float reduce slots
    __shared__ uint32_t candB[CAND];
    __shared__ int      candI[CAND];
    __shared__ uint32_t bT, bI;
    __shared__ float    bInv;
    __shared__ int      bFlag;

    hist[t] = 0;
    hsum[t] = 0.0f;
    if (t == 0) pcnt = 0;
    __syncthreads();                                          // B0 (zero)

    // ---- pass 1: stream row; counts, hist, bucket exp-sums, pool append
    int clo = 0;
    float sumHigh = 0.0f;
    {
        const uint4* wf = (const uint4*)rp;
#pragma unroll
        for (int j = 0; j < VPT; ++j) {
            const uint4 u = wf[j * BLOCK + t];
            const uint32_t bits[4] = {u.x, u.y, u.z, u.w};
#pragma unroll
            for (int c = 0; c < 4; ++c) {
                const uint32_t b = bits[c];
                const float f = __uint_as_float(b);
                const bool lo = (f < P1), hi = (f >= P2);
                clo += lo;
                if (hi) sumHigh += __expf(f);
                const bool in = !lo && !hi;
                const unsigned long long m = __ballot(in);
                if (m) {
                    if (in) {
                        const int bk = min((int)((f - P1) * BSCALE), NB - 1);
                        atomicAdd(&hist[bk], 1);
                        atomicAdd(&hsum[bk], __expf(f));
                    }
                    const int leader = __ffsll(m) - 1;
                    const int cnt = __popcll(m);
                    int base = 0;
                    if (lane == leader) base = atomicAdd(&pcnt, cnt);
                    base = __shfl(base, leader, 64);
                    if (in) {
                        const int slot =
                            base + __popcll(m & ((1ull << lane) - 1ull));
                        if (slot < POOL) {
                            const int idx = (j * BLOCK + t) * 4 + c;
                            pool[slot] = make_uint2(b, (uint32_t)idx);
                        }
                    }
                }
            }
        }
    }
#pragma unroll
    for (int off = 32; off > 0; off >>= 1) {
        clo += __shfl_xor(clo, off, 64);
        sumHigh += __shfl_xor(sumHigh, off, 64);
    }
    if (lane == 0) { wclo[wid] = clo; whigh[wid] = sumHigh; }
    __syncthreads();                                          // B1 (pass1)

    // ---- wave 0: scan, select crossing bucket, rank, analytic survivor sum
    if (wid == 0) {
        const int   cloB = wclo[0] + wclo[1] + wclo[2] + wclo[3];
        const float sumH = whigh[0] + whigh[1] + whigh[2] + whigh[3];
        const int4   hh = ((const int4*)hist)[lane];
        const float4 hs = ((const float4*)hsum)[lane];
        const int a0 = hh.x, a1 = a0 + hh.y, a2 = a1 + hh.z, a3 = a2 + hh.w;
        const float f0 = hs.x, f1 = f0 + hs.y, f2 = f1 + hs.z, f3 = f2 + hs.w;
        int sc = a3; float fc = f3;
#pragma unroll
        for (int off = 1; off < 64; off <<= 1) {
            const int   ui = __shfl_up(sc, off, 64);
            const float uf = __shfl_up(fc, off, 64);
            if (lane >= off) { sc += ui; fc += uf; }
        }
        const int   tot  = __shfl(sc, 63, 64);
        const float tot2 = __shfl(fc, 63, 64);
        const int   ibase = sc - a3;      // exclusive count prefix
        const float fbase = fc - f3;      // exclusive sum prefix

        bool ok = (cloB < KSEL) && (cloB + tot >= KSEL);
        int selb = -1, jms = 0; float sumAbove = 0.0f;
        if (ok) {
            const int jrank = KSEL - cloB;          // 1-indexed rank in band
            const int   inc[4] = {ibase + a0, ibase + a1, ibase + a2, ibase + a3};
            const int   exc[4] = {ibase, ibase + a0, ibase + a1, ibase + a2};
            const float fin[4] = {fbase + f0, fbase + f1, fbase + f2, fbase + f3};
#pragma unroll
            for (int i = 0; i < 4; ++i)
                if (exc[i] < jrank && jrank <= inc[i]) {
                    selb = lane * 4 + i;
                    jms  = jrank - exc[i] - 1;      // 0-indexed rank in bucket
                    sumAbove = tot2 - fin[i];       // exp-sum of buckets > selb
                }
            const unsigned long long bb = __ballot(selb >= 0);
            const int src = __ffsll(bb) - 1;
            selb = __shfl(selb, src, 64);
            jms  = __shfl(jms,  src, 64);
            sumAbove = __shfl(sumAbove, src, 64);
        }
        const int pn = pcnt;
        if (pn > POOL) ok = false;

        int cn = 0;
        if (ok) {
            for (int k = 0; k < pn; k += 64) {
                const int id = k + lane;
                const bool val = id < pn;
                uint32_t pb = 0, pi = 0;
                if (val) { const uint2 pe = pool[id]; pb = pe.x; pi = pe.y; }
                bool in = false;
                if (val) {
                    const float pf = __uint_as_float(pb);
                    in = (min((int)((pf - P1) * BSCALE), NB - 1) == selb);
                }
                const unsigned long long m = __ballot(in);
                if (in) {
                    const int slot = cn + __popcll(m & ((1ull << lane) - 1ull));
                    if (slot < CAND) { candB[slot] = pb; candI[slot] = (int)pi; }
                }
                cn += __popcll(m);
            }
            if (cn > CAND) ok = false;
        }
        if (ok) {
            __threadfence_block();
            bool found = false; uint32_t mT = 0; int mI = 0;
            if (lane < cn) {
                const uint32_t myb = candB[lane]; const int myi = candI[lane];
                int rank = 0;
                for (int q = 0; q < cn; ++q)
                    rank += (candB[q] < myb) ||
                            (candB[q] == myb && candI[q] < myi);
                if (rank == jms) { found = true; mT = myb; mI = myi; }
            }
            const unsigned long long bb = __ballot(found);
            const int src = __ffsll(bb) - 1;
            const uint32_t T = (uint32_t)__shfl((int)mT, src, 64);
            const int      ti = __shfl(mI, src, 64);
            float sb = 0.0f;                       // in-bucket survivor sum
            if (lane < cn) {
                const uint32_t cbv = candB[lane]; const int civ = candI[lane];
                if (cbv > T || (cbv == T && civ > ti))
                    sb = __expf(__uint_as_float(cbv));
            }
#pragma unroll
            for (int off = 32; off > 0; off >>= 1) sb += __shfl_xor(sb, off, 64);
            if (lane == 0) {
                bT = T; bI = (uint32_t)ti;
                bInv = 1.0f / (sumH + sumAbove + sb);
            }
        }
        if (lane == 0) bFlag = ok ? 0 : 1;
    }
    __syncthreads();                                          // B2 (threshold)

    // ---- exact fallback (block-uniform; never taken for uniform data)
    if (bFlag) {
        const uint4* wf = (const uint4*)rp;
        uint32_t blo = 0u, bhi = 0x7f7fffffu;
        while (blo < bhi) {
            const uint32_t mid = blo + ((bhi - blo) >> 1);
            int c = 0;
#pragma unroll
            for (int j = 0; j < VPT; ++j) {
                const uint4 u = wf[j * BLOCK + t];
                c += (u.x <= mid) + (u.y <= mid) + (u.z <= mid) + (u.w <= mid);
            }
#pragma unroll
            for (int off = 32; off > 0; off >>= 1) c += __shfl_xor(c, off, 64);
            if (lane == 0) wclo[wid] = c;
            __syncthreads();
            const int tot = wclo[0] + wclo[1] + wclo[2] + wclo[3];
            __syncthreads();
            if (tot >= KSEL) bhi = mid; else blo = mid + 1;
        }
        const uint32_t T = blo;
        int c = 0;
#pragma unroll
        for (int j = 0; j < VPT; ++j) {
            const uint4 u = wf[j * BLOCK + t];
            c += (u.x < T) + (u.y < T) + (u.z < T) + (u.w < T);
        }
#pragma unroll
        for (int off = 32; off > 0; off >>= 1) c += __shfl_xor(c, off, 64);
        if (lane == 0) wclo[wid] = c;
        __syncthreads();
        const int clt = wclo[0] + wclo[1] + wclo[2] + wclo[3];
        __syncthreads();
        const int need = KSEL - clt;
        int ilo = 0, ihi = N - 1;
        while (ilo < ihi) {
            const int imid = (ilo + ihi) >> 1;
            int cc = 0;
#pragma unroll
            for (int j = 0; j < VPT; ++j) {
                const uint4 u = wf[j * BLOCK + t];
                const int i0 = (j * BLOCK + t) * 4;
                cc += (u.x == T && i0 + 0 <= imid) + (u.y == T && i0 + 1 <= imid) +
                      (u.z == T && i0 + 2 <= imid) + (u.w == T && i0 + 3 <= imid);
            }
#pragma unroll
            for (int off = 32; off > 0; off >>= 1) cc += __shfl_xor(cc, off, 64);
            if (lane == 0) wclo[wid] = cc;
            __syncthreads();
            const int tot = wclo[0] + wclo[1] + wclo[2] + wclo[3];
            __syncthreads();
            if (tot >= need) ihi = imid; else ilo = imid + 1;
        }
        // survivor sum pass
        float acc = 0.0f;
#pragma unroll
        for (int j = 0; j < VPT; ++j) {
            const uint4 u = wf[j * BLOCK + t];
            const uint32_t bits[4] = {u.x, u.y, u.z, u.w};
            const int i0 = (j * BLOCK + t) * 4;
#pragma unroll
            for (int cc2 = 0; cc2 < 4; ++cc2) {
                const bool keep = (bits[cc2] > T) ||
                                  (bits[cc2] == T && i0 + cc2 > ilo);
                if (keep) acc += __expf(__uint_as_float(bits[cc2]));
            }
        }
#pragma unroll
        for (int off = 32; off > 0; off >>= 1) acc += __shfl_xor(acc, off, 64);
        if (lane == 0) whigh[wid] = acc;
        __syncthreads();
        if (t == 0) {
            bT = T; bI = (uint32_t)ilo;
            bInv = 1.0f / (whigh[0] + whigh[1] + whigh[2] + whigh[3]);
        }
        __syncthreads();
    }

    // ---- pass 2: re-read row (L2-hot), keep -> exp*inv, NT store
    const uint32_t T = bT; const int ti = (int)bI; const float inv = bInv;
    const uint4* wf = (const uint4*)rp;
    vfloat4* of = (vfloat4*)(out + row * N);
#pragma unroll
    for (int j = 0; j < VPT; ++j) {
        const uint4 u = wf[j * BLOCK + t];
        const uint32_t bits[4] = {u.x, u.y, u.z, u.w};
        const int i0 = (j * BLOCK + t) * 4;
        vfloat4 o;
#pragma unroll
        for (int c = 0; c < 4; ++c) {
            const uint32_t b = bits[c];
            const bool keep = (b > T) || (b == T && i0 + c > ti);
            o[c] = keep ? __expf(__uint_as_float(b)) * inv : 0.0f;
        }
        __builtin_nontemporal_store(o, &of[j * BLOCK + t]);
    }
}

extern "C" void kernel_launch(void* const* d_in, const int* in_sizes, int n_in,
                              void* d_out, int out_size, void* d_ws, size_t ws_size,
                              hipStream_t stream) {
    const float* w = (const float*)d_in[0];
    float* out = (float*)d_out;
    const int rows = in_sizes[0] / N;            // 8192
    wdrop_kernel<<<rows, BLOCK, 0, stream>>>(w, out);
}